// Round 3
// baseline (172.752 us; speedup 1.0000x reference)
//
#include <hip/hip_runtime.h>

// ---- constants -------------------------------------------------------------
#define BATCH 4
#define SEQ   1024
#define KENC  512
#define HDIM  1024
#define NHEAD 16
#define HD    64
#define LOG2E 1.44269504088896340736f

typedef __attribute__((ext_vector_type(8))) short bf16x8;
typedef __attribute__((ext_vector_type(4))) float f32x4;
typedef __attribute__((ext_vector_type(4))) float f4v;
typedef __attribute__((ext_vector_type(4))) short s4v;

__device__ __forceinline__ short f2bf(float f) {
  unsigned u = __float_as_uint(f);
  u += 0x7fffu + ((u >> 16) & 1u);   // RNE
  return (short)(u >> 16);
}

__device__ __forceinline__ void gload_lds16(const void* g, void* l) {
  __builtin_amdgcn_global_load_lds(
      (const __attribute__((address_space(1))) void*)g,
      (__attribute__((address_space(3))) void*)l, 16, 0, 0);
}

// DPP-based 16-lane reductions (VALU pipe, frees DS pipe)
template <int C>
__device__ __forceinline__ float dppf(float x) {
  return __int_as_float(
      __builtin_amdgcn_update_dpp(0, __float_as_int(x), C, 0xF, 0xF, false));
}
__device__ __forceinline__ float red16_max(float x) {
  x = fmaxf(x, dppf<0xB1>(x));
  x = fmaxf(x, dppf<0x4E>(x));
  x = fmaxf(x, dppf<0x141>(x));
  x = fmaxf(x, dppf<0x140>(x));
  return x;
}
__device__ __forceinline__ float red16_sum(float x) {
  x += dppf<0xB1>(x);
  x += dppf<0x4E>(x);
  x += dppf<0x141>(x);
  x += dppf<0x140>(x);
  return x;
}

// ---- kernel 1: f32 -> bf16 cast (vectorized) -------------------------------
__global__ __launch_bounds__(256) void cast_bf16(const float* __restrict__ src,
                                                 short* __restrict__ dst, int n4) {
  int i = blockIdx.x * 256 + threadIdx.x;
  if (i >= n4) return;
  f4v v = ((const f4v*)src)[i];
  s4v o;
#pragma unroll
  for (int j = 0; j < 4; ++j) o[j] = f2bf(v[j]);
  ((s4v*)dst)[i] = o;
}

// ---- kernel 2: weight cast + transpose: Wt[n][k] = W[k][n] -----------------
struct WtArgs { const float* W[6]; };

__global__ __launch_bounds__(256) void wt_cast(WtArgs a, short* __restrict__ wt) {
  int j = blockIdx.z;
  const float* W = a.W[j];
  short* dst = wt + (size_t)j * (HDIM * HDIM);
  int cb = blockIdx.x * 32, rb = blockIdx.y * 32;
  __shared__ float t[32][33];
  int tx = threadIdx.x & 31, ty = threadIdx.x >> 5;
#pragma unroll
  for (int rr = 0; rr < 4; ++rr)
    t[ty + rr * 8][tx] = W[(size_t)(rb + ty + rr * 8) * HDIM + cb + tx];
  __syncthreads();
#pragma unroll
  for (int rr = 0; rr < 4; ++rr)
    dst[(size_t)(cb + ty + rr * 8) * HDIM + rb + tx] = f2bf(t[tx][ty + rr * 8]);
}

// ---- kernel 3: fused projection GEMM, 256x256 tile, BK=32, quad-buffer -----
// job0: hbf[4096x1024] x wt[0..4095]  (q,k,v,kq)   grid 16x16
// job1: ebf[2048x1024] x wt[4096..6143] (kk,kv)    grid 8x8
// 8 waves (2M x 4N), per-wave 128x64 C. Counted vmcnt(8): stage tile t+3
// while computing tile t, 4 LDS buffers of 32KB.
struct GemmArgs {
  const short* X[2];
  const short* W[2];
  const float* bias[6];
  short* out[6];
  float scale[6];
};

__global__ __launch_bounds__(512, 2) void proj_gemm8(GemmArgs a) {
  __shared__ __align__(16) char Lds[131072];

  int lid = blockIdx.x;
  int id = (lid & 7) * 40 + (lid >> 3);    // bijective XCD swizzle (320 = 8*40)
  int job, bm, bn;
  if (id < 256) { job = 0; bm = id >> 4; bn = id & 15; }
  else          { job = 1; int i2 = id - 256; bm = i2 >> 3; bn = i2 & 7; }

  const char* Xp = (const char*)a.X[job];
  const char* Wp = (const char*)a.W[job];

  int tid = threadIdx.x;
  int lane = tid & 63, w = tid >> 6;
  int l15 = lane & 15, g4 = lane >> 4;
  int wr = w >> 2, wc = w & 3;

  // ---- stage addressing (linear LDS dest, inverse-swizzled global source) --
  // half-tile = 128 rows x 32 K x 2B = 8KB = 512 thr x 16B (one gload each).
  // linear off = w*1024 + lane*16 -> row = w*16 + (lane>>2), phys slot = lane&3
  // logical slot = phys ^ ((row>>1)&3) = (lane&3) ^ ((lane>>3)&3)
  int srow = w * 16 + (lane >> 2);
  int sslot = (lane & 3) ^ ((lane >> 3) & 3);
  size_t sa0 = ((size_t)(bm * 256 + srow)) * 2048 + sslot * 16;
  size_t sa1 = ((size_t)(bm * 256 + 128 + srow)) * 2048 + sslot * 16;
  size_t sb0 = ((size_t)(bn * 256 + srow)) * 2048 + sslot * 16;
  size_t sb1 = ((size_t)(bn * 256 + 128 + srow)) * 2048 + sslot * 16;
  // LDS dests within a 32KB buffer: A-h0 0, A-h1 8K, B-h0 16K, B-h1 24K
  int ldA0 = w * 1024, ldA1 = 8192 + w * 1024;
  int ldB0 = 16384 + w * 1024, ldB1 = 24576 + w * 1024;

  // ---- fragment read offsets (swizzled) ------------------------------------
  // frag (m): row = m*16+l15, byte = row*64 + ((g4 ^ ((row>>1)&3))<<4)
  int slotR = (l15 >> 1) & 3;
  int aoff = wr * 8192 + l15 * 64 + ((g4 ^ slotR) << 4);
  int boff = 16384 + (wc >> 1) * 8192 + ((wc & 1) * 64 + l15) * 64 +
             ((g4 ^ slotR) << 4);

  f32x4 acc[8][4];
#pragma unroll
  for (int m = 0; m < 8; ++m)
#pragma unroll
    for (int n = 0; n < 4; ++n)
#pragma unroll
      for (int r = 0; r < 4; ++r) acc[m][n][r] = 0.0f;

#define STG_A(bufo, kof)                                      \
  do {                                                        \
    gload_lds16(Xp + sa0 + (kof), Lds + (bufo) + ldA0);       \
    gload_lds16(Xp + sa1 + (kof), Lds + (bufo) + ldA1);       \
  } while (0)
#define STG_B(bufo, kof)                                      \
  do {                                                        \
    gload_lds16(Wp + sb0 + (kof), Lds + (bufo) + ldB0);       \
    gload_lds16(Wp + sb1 + (kof), Lds + (bufo) + ldB1);       \
  } while (0)

  // prologue: stage tiles 0,1,2 into bufs 0,1,2 (12 loads); wait tile0 (8 left)
  STG_A(0, 0);       STG_B(0, 0);
  STG_A(32768, 64);  STG_B(32768, 64);
  STG_A(65536, 128); STG_B(65536, 128);
  asm volatile("s_waitcnt vmcnt(8)" ::: "memory");
  __builtin_amdgcn_s_barrier();
  asm volatile("" ::: "memory");

  bf16x8 afr[4], bfr[4];

#define PHASE0(bo, DO_STG, sbo, kof)                                           \
  do {                                                                         \
    _Pragma("unroll") for (int m = 0; m < 4; ++m)                              \
        afr[m] = *(const bf16x8*)(Lds + (bo) + m * 1024 + aoff);               \
    _Pragma("unroll") for (int n = 0; n < 4; ++n)                              \
        bfr[n] = *(const bf16x8*)(Lds + (bo) + n * 1024 + boff);               \
    if (DO_STG) STG_A(sbo, kof);                                               \
    __builtin_amdgcn_s_barrier();                                              \
    __builtin_amdgcn_s_setprio(1);                                             \
    _Pragma("unroll") for (int m = 0; m < 4; ++m)                              \
        _Pragma("unroll") for (int n = 0; n < 4; ++n)                          \
            acc[m][n] = __builtin_amdgcn_mfma_f32_16x16x32_bf16(               \
                afr[m], bfr[n], acc[m][n], 0, 0, 0);                           \
    __builtin_amdgcn_s_setprio(0);                                             \
    __builtin_amdgcn_s_barrier();                                              \
  } while (0)

#define PHASE1(bo, DO_STG, sbo, kof, VMW)                                      \
  do {                                                                         \
    _Pragma("unroll") for (int m = 0; m < 4; ++m)                              \
        afr[m] = *(const bf16x8*)(Lds + (bo) + (m + 4) * 1024 + aoff);         \
    if (DO_STG) STG_B(sbo, kof);                                               \
    __builtin_amdgcn_s_barrier();                                              \
    __builtin_amdgcn_s_setprio(1);                                             \
    _Pragma("unroll") for (int m = 0; m < 4; ++m)                              \
        _Pragma("unroll") for (int n = 0; n < 4; ++n)                          \
            acc[m + 4][n] = __builtin_amdgcn_mfma_f32_16x16x32_bf16(           \
                afr[m], bfr[n], acc[m + 4][n], 0, 0, 0);                       \
    __builtin_amdgcn_s_setprio(0);                                             \
    asm volatile(VMW ::: "memory");                                            \
    __builtin_amdgcn_s_barrier();                                              \
    asm volatile("" ::: "memory");                                             \
  } while (0)

#pragma unroll 1
  for (int t = 0; t < 29; ++t) {
    int bo = (t & 3) << 15;
    int sbo = ((t + 3) & 3) << 15;
    int kof = (t + 3) * 64;
    PHASE0(bo, 1, sbo, kof);
    PHASE1(bo, 1, sbo, kof, "s_waitcnt vmcnt(8)");
  }
  // tail: tiles 29,30,31 (no staging; drain counted)
  PHASE0((29 & 3) << 15, 0, 0, 0);
  PHASE1((29 & 3) << 15, 0, 0, 0, "s_waitcnt vmcnt(4)");
  PHASE0((30 & 3) << 15, 0, 0, 0);
  PHASE1((30 & 3) << 15, 0, 0, 0, "s_waitcnt vmcnt(0)");
  PHASE0((31 & 3) << 15, 0, 0, 0);
  PHASE1((31 & 3) << 15, 0, 0, 0, "s_nop 0");

  // ---- epilogue: bias + scale + per-head scatter ---------------------------
  int hg = bn * 4 + wc;
  int jj = (job ? 4 : 0) + (hg >> 4);
  int head = hg & 15;
  int tsh = job ? 9 : 10;
  int tmask = (1 << tsh) - 1;
  const float* bias = a.bias[jj];
  float scl = a.scale[jj];
  short* out = a.out[jj];
  int mode = (jj == 2 || jj == 5) ? 1 : 0;

  float bv[4];
#pragma unroll
  for (int n = 0; n < 4; ++n) bv[n] = bias[head * 64 + n * 16 + l15];

  int rowb = bm * 256 + wr * 128 + g4 * 4;
  if (mode == 0) {
#pragma unroll
    for (int m = 0; m < 8; ++m)
#pragma unroll
      for (int n = 0; n < 4; ++n) {
        int d = n * 16 + l15;
#pragma unroll
        for (int r = 0; r < 4; ++r) {
          int row = rowb + m * 16 + r;
          int bb = row >> tsh, tt = row & tmask;
          float val = (acc[m][n][r] + bv[n]) * scl;
          out[((((size_t)bb * NHEAD + head) << tsh) + tt) * 64 + d] = f2bf(val);
        }
      }
  } else {
#pragma unroll
    for (int m = 0; m < 8; ++m)
#pragma unroll
      for (int n = 0; n < 4; ++n) {
        int d = n * 16 + l15;
#pragma unroll
        for (int r = 0; r < 4; ++r) {
          int row = rowb + m * 16 + r;
          int bb = row >> tsh, tt = row & tmask;
          float val = (acc[m][n][r] + bv[n]) * scl;
          out[((((size_t)bb * NHEAD + head) * 64 + d) << tsh) + tt] = f2bf(val);
        }
      }
  }
#undef STG_A
#undef STG_B
#undef PHASE0
#undef PHASE1
}

// ---- kernel 4: fused dual-branch flash attention (2-phase pipeline) --------
__global__ __launch_bounds__(256, 3) void attn_kernel(
    const short* __restrict__ qall, const short* __restrict__ kall,
    const short* __restrict__ vTall, const short* __restrict__ kqall,
    const short* __restrict__ kkall, const short* __restrict__ kvTall,
    const float* __restrict__ amask, const float* __restrict__ emask,
    float* __restrict__ out) {
  __shared__ short Ks[2 * 64 * 64];
  __shared__ short Vs[2 * 64 * 64];
  __shared__ short Ps[4 * 16 * 64];

  int lid = blockIdx.x;
  int id = ((lid & 7) << 7) | (lid >> 3);
  int bh = id >> 4, qb = id & 15;
  int b = bh >> 4, h = bh & 15;
  int lane = threadIdx.x & 63, wave = threadIdx.x >> 6;
  int l15 = lane & 15, g4 = lane >> 4, l7 = lane & 7;
  int srow = lane >> 3;
  int scol = (l7 ^ srow) * 8;
  int qbase = qb * 64;
  char* Pw = (char*)(Ps + wave * 1024);

  const short* qp  = qall  + ((size_t)bh * SEQ + qbase + wave * 16) * 64;
  const short* kqp = kqall + ((size_t)bh * SEQ + qbase + wave * 16) * 64;
  bf16x8 qf0  = *(const bf16x8*)(qp  + l15 * 64 + g4 * 8);
  bf16x8 qf1  = *(const bf16x8*)(qp  + l15 * 64 + 32 + g4 * 8);
  bf16x8 kqf0 = *(const bf16x8*)(kqp + l15 * 64 + g4 * 8);
  bf16x8 kqf1 = *(const bf16x8*)(kqp + l15 * 64 + 32 + g4 * 8);

  const short* kp0 = kall   + (size_t)bh * SEQ * 64;
  const short* vp0 = vTall  + (size_t)bh * 64 * SEQ;
  const short* kp1 = kkall  + (size_t)bh * KENC * 64;
  const short* vp1 = kvTall + (size_t)bh * 64 * KENC;

  bf16x8 qc0 = qf0, qc1 = qf1;
  const float* mpc = amask + (size_t)b * SEQ;

  auto STAGE = [&](int pb, const short* kptr, const short* vptr, int Tt, int kt) {
#pragma unroll
    for (int cc = 0; cc < 2; ++cc) {
      int c = wave * 2 + cc;
      int row = c * 8 + srow;
      gload_lds16(kptr + (size_t)(kt * 64 + row) * 64 + scol,
                  (char*)Ks + pb * 8192 + c * 1024);
      gload_lds16(vptr + (size_t)row * Tt + kt * 64 + scol,
                  (char*)Vs + pb * 8192 + c * 1024);
    }
  };

  STAGE(0, kp0, vp0, SEQ, 0);

  f32x4 ctx[4], c1[4], mr, lr;
#pragma unroll
  for (int i = 0; i < 4; ++i) {
#pragma unroll
    for (int r = 0; r < 4; ++r) { ctx[i][r] = 0.0f; c1[i][r] = 0.0f; }
    mr[i] = -1e30f;
    lr[i] = 0.0f;
  }

#pragma unroll 2
  for (int t = 0; t < 24; ++t) {
    int p = t & 1;
    __syncthreads();
    if (t < 23) {
      int tn = t + 1;
      bool nb = tn >= 16;
      const short* skp = nb ? kp1 : kp0;
      const short* svp = nb ? vp1 : vp0;
      int sT = nb ? KENC : SEQ;
      int skt = nb ? tn - 16 : tn;
      STAGE(p ^ 1, skp, svp, sT, skt);
    }
    if (t == 16) {
#pragma unroll
      for (int dt = 0; dt < 4; ++dt) {
#pragma unroll
        for (int r = 0; r < 4; ++r) {
          c1[dt][r] = ctx[dt][r] * __builtin_amdgcn_rcpf(lr[r]);
          ctx[dt][r] = 0.0f;
        }
      }
#pragma unroll
      for (int r = 0; r < 4; ++r) { mr[r] = -1e30f; lr[r] = 0.0f; }
      qc0 = kqf0;
      qc1 = kqf1;
      mpc = emask + (size_t)b * KENC;
    }
    int kt = (t >= 16) ? t - 16 : t;
    const char* Kb = (const char*)Ks + p * 8192;
    const char* Vb = (const char*)Vs + p * 8192;

    float mk[4];
#pragma unroll
    for (int t2 = 0; t2 < 4; ++t2) mk[t2] = mpc[kt * 64 + t2 * 16 + l15] * LOG2E;

    f32x4 sc[4];
#pragma unroll
    for (int t2 = 0; t2 < 4; ++t2)
#pragma unroll
      for (int r = 0; r < 4; ++r) sc[t2][r] = 0.0f;

    __builtin_amdgcn_s_setprio(1);
#pragma unroll
    for (int t2 = 0; t2 < 4; ++t2) {
      bf16x8 kf0 = *(const bf16x8*)(Kb + (t2 * 16 + l15) * 128 + ((g4 ^ l7) << 4));
      bf16x8 kf1 = *(const bf16x8*)(Kb + (t2 * 16 + l15) * 128 + (((4 + g4) ^ l7) << 4));
      sc[t2] = __builtin_amdgcn_mfma_f32_16x16x32_bf16(qc0, kf0, sc[t2], 0, 0, 0);
      sc[t2] = __builtin_amdgcn_mfma_f32_16x16x32_bf16(qc1, kf1, sc[t2], 0, 0, 0);
    }
    __builtin_amdgcn_s_setprio(0);

#pragma unroll
    for (int t2 = 0; t2 < 4; ++t2)
#pragma unroll
      for (int r = 0; r < 4; ++r) sc[t2][r] += mk[t2];

    f32x4 rm;
#pragma unroll
    for (int r = 0; r < 4; ++r)
      rm[r] = fmaxf(fmaxf(sc[0][r], sc[1][r]), fmaxf(sc[2][r], sc[3][r]));
#pragma unroll
    for (int r = 0; r < 4; ++r) rm[r] = red16_max(rm[r]);

    int need = (rm[0] > mr[0] + 12.f) || (rm[1] > mr[1] + 12.f) ||
               (rm[2] > mr[2] + 12.f) || (rm[3] > mr[3] + 12.f);
    if (__any(need)) {
#pragma unroll
      for (int r = 0; r < 4; ++r) {
        float mn = fmaxf(mr[r], rm[r]);
        float s = __builtin_amdgcn_exp2f(mr[r] - mn);
        mr[r] = mn;
        lr[r] *= s;
        ctx[0][r] *= s; ctx[1][r] *= s; ctx[2][r] *= s; ctx[3][r] *= s;
      }
    }

    f32x4 pv[4], rs;
#pragma unroll
    for (int r = 0; r < 4; ++r) rs[r] = 0.0f;
#pragma unroll
    for (int t2 = 0; t2 < 4; ++t2)
#pragma unroll
      for (int r = 0; r < 4; ++r) {
        pv[t2][r] = __builtin_amdgcn_exp2f(sc[t2][r] - mr[r]);
        rs[r] += pv[t2][r];
      }
#pragma unroll
    for (int r = 0; r < 4; ++r) lr[r] += red16_sum(rs[r]);

#pragma unroll
    for (int t2 = 0; t2 < 4; ++t2) {
      int gg = t2 * 2 + (l15 >> 3);
#pragma unroll
      for (int r4 = 0; r4 < 4; ++r4) {
        int rr = g4 * 4 + r4;
        *(short*)(Pw + rr * 128 + (((gg ^ (rr & 7)) << 4) | (l7 * 2))) =
            f2bf(pv[t2][r4]);
      }
    }
    __builtin_amdgcn_s_setprio(1);
#pragma unroll
    for (int kc = 0; kc < 2; ++kc) {
      bf16x8 pf = *(const bf16x8*)(Pw + l15 * 128 + (((kc * 4 + g4) ^ l7) << 4));
#pragma unroll
      for (int dt = 0; dt < 4; ++dt) {
        bf16x8 vf = *(const bf16x8*)(Vb + (dt * 16 + l15) * 128 +
                                     (((kc * 4 + g4) ^ l7) << 4));
        ctx[dt] = __builtin_amdgcn_mfma_f32_16x16x32_bf16(pf, vf, ctx[dt], 0, 0, 0);
      }
    }
    __builtin_amdgcn_s_setprio(0);
  }

#pragma unroll
  for (int dt = 0; dt < 4; ++dt)
#pragma unroll
    for (int r = 0; r < 4; ++r) {
      float v2 = ctx[dt][r] * __builtin_amdgcn_rcpf(lr[r]);
      int s = qbase + wave * 16 + g4 * 4 + r;
      int d = dt * 16 + l15;
      out[((size_t)b * SEQ + s) * HDIM + h * 64 + d] = 0.5f * (c1[dt][r] + v2);
    }
}

// ---- host launcher ---------------------------------------------------------
extern "C" void kernel_launch(void* const* d_in, const int* in_sizes, int n_in,
                              void* d_out, int out_size, void* d_ws, size_t ws_size,
                              hipStream_t stream) {
  const float* hid = (const float*)d_in[0];
  const float* enc = (const float*)d_in[1];
  const float* amask = (const float*)d_in[2];
  const float* emask = (const float*)d_in[3];

  char* ws = (char*)d_ws;
  short* hbf = (short*)(ws);                        // 8 MB  [B*S,H] bf16
  short* ebf = (short*)(ws + (8u << 20));           // 4 MB  [B*K,H]
  short* wt = (short*)(ws + (12u << 20));           // 12 MB 6x [n][k]
  short* qo = (short*)(ws + (24u << 20));           // 8 MB  [B,NH,S,HD]
  short* ko = (short*)(ws + (32u << 20));           // 8 MB
  short* vT = (short*)(ws + (40u << 20));           // 8 MB  [B,NH,HD,S]
  short* kqo = (short*)(ws + (48u << 20));          // 8 MB
  short* kko = (short*)(ws + (56u << 20));          // 4 MB  [B,NH,K,HD]
  short* kvT = (short*)(ws + (60u << 20));          // 4 MB  [B,NH,HD,K]

  cast_bf16<<<4096, 256, 0, stream>>>(hid, hbf, (BATCH * SEQ * HDIM) / 4);
  cast_bf16<<<2048, 256, 0, stream>>>(enc, ebf, (BATCH * KENC * HDIM) / 4);

  WtArgs wa;
  for (int j = 0; j < 6; ++j) wa.W[j] = (const float*)d_in[4 + 2 * j];
  wt_cast<<<dim3(32, 32, 6), 256, 0, stream>>>(wa, wt);

  GemmArgs ga;
  ga.X[0] = hbf; ga.X[1] = ebf;
  ga.W[0] = wt;  ga.W[1] = wt + (size_t)4 * HDIM * HDIM;
  short* outs[6] = {qo, ko, vT, kqo, kko, kvT};
  const float qscale = 0.125f * LOG2E;
  const float scl[6] = {qscale, 1.f, 1.f, qscale, 1.f, 1.f};
  for (int j = 0; j < 6; ++j) {
    ga.bias[j] = (const float*)d_in[5 + 2 * j];
    ga.out[j] = outs[j];
    ga.scale[j] = scl[j];
  }
  proj_gemm8<<<320, 512, 0, stream>>>(ga);

  attn_kernel<<<1024, 256, 0, stream>>>(qo, ko, vT, kqo, kko, kvT, amask, emask,
                                        (float*)d_out);
}

// Round 4
// 147.629 us; speedup vs baseline: 1.1702x; 1.1702x over previous
//
#include <hip/hip_runtime.h>

// ---- constants -------------------------------------------------------------
#define BATCH 4
#define SEQ   1024
#define KENC  512
#define HDIM  1024
#define NHEAD 16
#define HD    64
#define LOG2E 1.44269504088896340736f

typedef __attribute__((ext_vector_type(8))) short bf16x8;
typedef __attribute__((ext_vector_type(4))) float f32x4;
typedef __attribute__((ext_vector_type(16))) float f32x16;
typedef __attribute__((ext_vector_type(4))) float f4v;
typedef __attribute__((ext_vector_type(4))) short s4v;

__device__ __forceinline__ short f2bf(float f) {
  unsigned u = __float_as_uint(f);
  u += 0x7fffu + ((u >> 16) & 1u);   // RNE
  return (short)(u >> 16);
}

__device__ __forceinline__ void gload_lds16(const void* g, void* l) {
  __builtin_amdgcn_global_load_lds(
      (const __attribute__((address_space(1))) void*)g,
      (__attribute__((address_space(3))) void*)l, 16, 0, 0);
}

// ---- kernel 1: f32 -> bf16 cast (vectorized) -------------------------------
__global__ __launch_bounds__(256) void cast_bf16(const float* __restrict__ src,
                                                 short* __restrict__ dst, int n4) {
  int i = blockIdx.x * 256 + threadIdx.x;
  if (i >= n4) return;
  f4v v = ((const f4v*)src)[i];
  s4v o;
#pragma unroll
  for (int j = 0; j < 4; ++j) o[j] = f2bf(v[j]);
  ((s4v*)dst)[i] = o;
}

// ---- kernel 2: weight cast + transpose: Wt[n][k] = W[k][n] -----------------
struct WtArgs { const float* W[6]; };

__global__ __launch_bounds__(256) void wt_cast(WtArgs a, short* __restrict__ wt) {
  int j = blockIdx.z;
  const float* W = a.W[j];
  short* dst = wt + (size_t)j * (HDIM * HDIM);
  int cb = blockIdx.x * 32, rb = blockIdx.y * 32;
  __shared__ float t[32][33];
  int tx = threadIdx.x & 31, ty = threadIdx.x >> 5;
#pragma unroll
  for (int rr = 0; rr < 4; ++rr)
    t[ty + rr * 8][tx] = W[(size_t)(rb + ty + rr * 8) * HDIM + cb + tx];
  __syncthreads();
#pragma unroll
  for (int rr = 0; rr < 4; ++rr)
    dst[(size_t)(cb + ty + rr * 8) * HDIM + rb + tx] = f2bf(t[tx][ty + rr * 8]);
}

// ---- kernel 3: batched projection GEMM (128x128 tile, BK=32) — round-2 ----
struct ProjArgs {
  const short* X[6];
  const short* Wt[6];
  const float* bias[6];
  short* out[6];
  int M[6];
  int tshift[6];  // log2(tokens): 10 or 9
  int mode[6];    // 0 std, 1 transposed
  float scale[6]; // epilogue scale (0.125*log2e for q/kq)
};

__global__ __launch_bounds__(256) void proj_gemm(ProjArgs a) {
  int job = blockIdx.z;
  int M = a.M[job];
  int by = blockIdx.y;
  if (by * 128 >= M) return;
  int bx = blockIdx.x;
  const short* X = a.X[job];
  const short* W = a.Wt[job];

  __shared__ short As[128 * 32];
  __shared__ short Bs[128 * 32];

  int tid = threadIdx.x, lane = tid & 63, wave = tid >> 6;
  int wr = wave >> 1, wc = wave & 1;
  int l15 = lane & 15, g4 = lane >> 4;

  f32x4 acc[4][4];
#pragma unroll
  for (int m = 0; m < 4; ++m)
#pragma unroll
    for (int n = 0; n < 4; ++n)
#pragma unroll
      for (int r = 0; r < 4; ++r) acc[m][n][r] = 0.0f;

  int arow = by * 128, brow = bx * 128;
  const int crow = lane >> 2;
  const int sgrp = (lane & 3) ^ ((lane >> 2) & 3) ^ (lane >> 4);
  const int rsw = (lane & 3) ^ ((l15) >> 2);

  for (int k0 = 0; k0 < HDIM; k0 += 32) {
#pragma unroll
    for (int cc = 0; cc < 2; ++cc) {
      int c = wave * 2 + cc;
      gload_lds16(X + (size_t)(arow + c * 16 + crow) * HDIM + k0 + sgrp * 8,
                  (char*)As + c * 1024);
      gload_lds16(W + (size_t)(brow + c * 16 + crow) * HDIM + k0 + sgrp * 8,
                  (char*)Bs + c * 1024);
    }
    __syncthreads();
    bf16x8 af[4], bfr[4];
#pragma unroll
    for (int m = 0; m < 4; ++m)
      af[m] = *(const bf16x8*)((const char*)As + (wr * 64 + m * 16 + l15) * 64 +
                               ((g4 ^ rsw) << 4));
#pragma unroll
    for (int n = 0; n < 4; ++n)
      bfr[n] = *(const bf16x8*)((const char*)Bs + (wc * 64 + n * 16 + l15) * 64 +
                                ((g4 ^ rsw) << 4));
#pragma unroll
    for (int m = 0; m < 4; ++m)
#pragma unroll
      for (int n = 0; n < 4; ++n)
        acc[m][n] = __builtin_amdgcn_mfma_f32_16x16x32_bf16(af[m], bfr[n],
                                                            acc[m][n], 0, 0, 0);
    __syncthreads();
  }

  const float* bias = a.bias[job];
  short* out = a.out[job];
  int tshift = a.tshift[job], tmask = (1 << tshift) - 1, mode = a.mode[job];
  float scl = a.scale[job];
#pragma unroll
  for (int m = 0; m < 4; ++m) {
    int rowb = arow + wr * 64 + m * 16 + (g4 << 2);
#pragma unroll
    for (int n = 0; n < 4; ++n) {
      int col = brow + wc * 64 + n * 16 + l15;
      float bv = bias[col];
      int head = col >> 6, d = col & 63;
#pragma unroll
      for (int r = 0; r < 4; ++r) {
        int row = rowb + r;
        int bb = row >> tshift, t = row & tmask;
        float val = (acc[m][n][r] + bv) * scl;
        size_t idx;
        if (mode == 0)
          idx = ((((size_t)bb * NHEAD + head) << tshift) + t) * 64 + d;
        else
          idx = ((((size_t)bb * NHEAD + head) * 64 + d) << tshift) + t;
        out[idx] = f2bf(val);
      }
    }
  }
}

// ---- kernel 4: swapped-QK^T 32x32 flash attention --------------------------
// 4 waves/block, wave = 32 q-rows. mfma(K,Q) -> lane owns q=l31's P-row half;
// softmax lane-local (+1 shfl_xor(32)); P->A-frags in-register via cvt_pk +
// 4 shfl exchanges; PV uses vT from LDS. K/V double-buffered, pre-swizzled
// global_load_lds staging. m/l per-lane scalars; ctx rescale deferred (THR=12).
__global__ __launch_bounds__(256, 3) void attn32(
    const short* __restrict__ qall, const short* __restrict__ kall,
    const short* __restrict__ vTall, const short* __restrict__ kqall,
    const short* __restrict__ kkall, const short* __restrict__ kvTall,
    const float* __restrict__ amask, const float* __restrict__ emask,
    float* __restrict__ out) {
  __shared__ char KT[2][8192];        // [64 kpos][128B], XOR-swizzled slots
  __shared__ char VT[2][8192];        // [64 d][128B k-window]
  __shared__ float red[4][32];        // per-wave q-row broadcast scratch

  int lid = blockIdx.x;
  int id = (lid & 7) * 64 + (lid >> 3);  // all 8 q-blocks of a bh -> same XCD
  int bh = id >> 3, qb = id & 7;
  int b = bh >> 4, h = bh & 15;
  int lane = threadIdx.x & 63, wave = threadIdx.x >> 6;
  int l31 = lane & 31, hi = lane >> 5, x7 = l31 & 7;
  int qrow0 = qb * 128 + wave * 32;

  // Q fragments: lane holds Q[q=l31][d = 16*i + 8*hi .. +8]
  bf16x8 qcur[4];
  {
    const short* qp = qall + ((size_t)bh * SEQ + qrow0 + l31) * 64;
#pragma unroll
    for (int i = 0; i < 4; ++i)
      qcur[i] = *(const bf16x8*)(qp + i * 16 + hi * 8);
  }

  const char* kb0 = (const char*)(kall + (size_t)bh * SEQ * 64);
  const char* vb0 = (const char*)(vTall + (size_t)bh * 64 * SEQ);
  const char* kb1 = (const char*)(kkall + (size_t)bh * KENC * 64);
  const char* vb1 = (const char*)(kvTall + (size_t)bh * 64 * KENC);
  const float* mpc = amask + (size_t)b * SEQ;

  auto STAGE = [&](int pb, const char* kb, const char* vb, size_t vrowb, int kt) {
    int t0 = threadIdx.x;
#pragma unroll
    for (int c = 0; c < 2; ++c) {
      int idx = c * 256 + t0;
      int row = idx >> 3, phys = idx & 7;
      int lg = phys ^ (row & 7);
      gload_lds16(kb + ((size_t)(kt * 64 + row)) * 128 + lg * 16,
                  KT[pb] + idx * 16);
      gload_lds16(vb + (size_t)row * vrowb + (size_t)kt * 128 + lg * 16,
                  VT[pb] + idx * 16);
    }
  };

  STAGE(0, kb0, vb0, SEQ * 2, 0);

  f32x16 ctx0, ctx1, c10, c11;
#pragma unroll
  for (int r = 0; r < 16; ++r) { ctx0[r] = 0.f; ctx1[r] = 0.f; c10[r] = 0.f; c11[r] = 0.f; }
  float mr = -1e30f, lr = 0.f;

#pragma unroll 1
  for (int t = 0; t < 24; ++t) {
    int p = t & 1;
    __syncthreads();                       // tile-t loads (issued last iter) landed
    if (t < 23) {
      int tn = t + 1;
      if (tn >= 16) STAGE(p ^ 1, kb1, vb1, KENC * 2, tn - 16);
      else          STAGE(p ^ 1, kb0, vb0, SEQ * 2, tn);
    }
    if (t == 16) {                         // finalize self branch
      if (!hi) red[wave][l31] = lr;
      asm volatile("s_waitcnt lgkmcnt(0)" ::: "memory");
#pragma unroll
      for (int r2 = 0; r2 < 4; ++r2) {
        f4v lv = *(const f4v*)(&red[wave][r2 * 8 + 4 * hi]);
#pragma unroll
        for (int j2 = 0; j2 < 4; ++j2) {
          float li = __builtin_amdgcn_rcpf(lv[j2]);
          int r = r2 * 4 + j2;
          c10[r] = ctx0[r] * li;  ctx0[r] = 0.f;
          c11[r] = ctx1[r] * li;  ctx1[r] = 0.f;
        }
      }
      mr = -1e30f; lr = 0.f;
      const short* kqp = kqall + ((size_t)bh * SEQ + qrow0 + l31) * 64;
#pragma unroll
      for (int i = 0; i < 4; ++i)
        qcur[i] = *(const bf16x8*)(kqp + i * 16 + hi * 8);
      mpc = emask + (size_t)b * KENC;
    }
    int kt = (t >= 16) ? t - 16 : t;
    const char* Kp = KT[p];
    const char* Vp = VT[p];

    // ---- QK^T (swapped): S^T[kpos][q], lane: q=l31, kpos per reg ----------
    f32x16 s0, s1;
#pragma unroll
    for (int r = 0; r < 16; ++r) { s0[r] = 0.f; s1[r] = 0.f; }
    __builtin_amdgcn_s_setprio(1);
#pragma unroll
    for (int i = 0; i < 4; ++i) {
      bf16x8 kf = *(const bf16x8*)(Kp + (l31)*128 + (((2 * i + hi) ^ x7) << 4));
      s0 = __builtin_amdgcn_mfma_f32_32x32x16_bf16(kf, qcur[i], s0, 0, 0, 0);
    }
#pragma unroll
    for (int i = 0; i < 4; ++i) {
      bf16x8 kf = *(const bf16x8*)(Kp + (32 + l31) * 128 + (((2 * i + hi) ^ x7) << 4));
      s1 = __builtin_amdgcn_mfma_f32_32x32x16_bf16(kf, qcur[i], s1, 0, 0, 0);
    }
    __builtin_amdgcn_s_setprio(0);

    // ---- mask add (log2 domain) -------------------------------------------
    const float* mp = mpc + kt * 64;
#pragma unroll
    for (int r2 = 0; r2 < 4; ++r2) {
      f4v ma = *(const f4v*)(mp + r2 * 8 + 4 * hi);
      f4v mb = *(const f4v*)(mp + 32 + r2 * 8 + 4 * hi);
#pragma unroll
      for (int j2 = 0; j2 < 4; ++j2) {
        s0[r2 * 4 + j2] = fmaf(ma[j2], LOG2E, s0[r2 * 4 + j2]);
        s1[r2 * 4 + j2] = fmaf(mb[j2], LOG2E, s1[r2 * 4 + j2]);
      }
    }

    // ---- online softmax: lane-local + one cross-half shfl -----------------
    float mx = s0[0];
#pragma unroll
    for (int r = 1; r < 16; ++r) mx = fmaxf(mx, s0[r]);
#pragma unroll
    for (int r = 0; r < 16; ++r) mx = fmaxf(mx, s1[r]);
    mx = fmaxf(mx, __int_as_float(__shfl_xor(__float_as_int(mx), 32)));

    if (!__all(mx <= mr + 12.f)) {         // rescale (rare: defer-max THR=12)
      float mn = fmaxf(mr, mx);
      float scl = __builtin_amdgcn_exp2f(mr - mn);
      mr = mn; lr *= scl;
      if (!hi) red[wave][l31] = scl;
      asm volatile("s_waitcnt lgkmcnt(0)" ::: "memory");
#pragma unroll
      for (int r2 = 0; r2 < 4; ++r2) {
        f4v sv = *(const f4v*)(&red[wave][r2 * 8 + 4 * hi]);
#pragma unroll
        for (int j2 = 0; j2 < 4; ++j2) {
          ctx0[r2 * 4 + j2] *= sv[j2];
          ctx1[r2 * 4 + j2] *= sv[j2];
        }
      }
    }

    float rs = 0.f;
#pragma unroll
    for (int r = 0; r < 16; ++r) { s0[r] = __builtin_amdgcn_exp2f(s0[r] - mr); rs += s0[r]; }
#pragma unroll
    for (int r = 0; r < 16; ++r) { s1[r] = __builtin_amdgcn_exp2f(s1[r] - mr); rs += s1[r]; }
    rs += __int_as_float(__shfl_xor(__float_as_int(rs), 32));
    lr += rs;

    // ---- P -> bf16 A-frags in-register, PV ---------------------------------
#pragma unroll
    for (int s = 0; s < 2; ++s) {
      const f32x16& sv = s ? s1 : s0;
      unsigned W[8];
#pragma unroll
      for (int r2 = 0; r2 < 4; ++r2) {
        asm("v_cvt_pk_bf16_f32 %0, %1, %2"
            : "=v"(W[r2 * 2]) : "v"(sv[r2 * 4 + 0]), "v"(sv[r2 * 4 + 1]));
        asm("v_cvt_pk_bf16_f32 %0, %1, %2"
            : "=v"(W[r2 * 2 + 1]) : "v"(sv[r2 * 4 + 2]), "v"(sv[r2 * 4 + 3]));
      }
#pragma unroll
      for (int jr = 0; jr < 2; ++jr) {
        unsigned sendA = hi ? W[(2 * jr) * 2]     : W[(2 * jr + 1) * 2];
        unsigned sendB = hi ? W[(2 * jr) * 2 + 1] : W[(2 * jr + 1) * 2 + 1];
        unsigned rA = (unsigned)__shfl_xor((int)sendA, 32);
        unsigned rB = (unsigned)__shfl_xor((int)sendB, 32);
        union { unsigned u[4]; bf16x8 v; } pa;
        if (!hi) { pa.u[0] = W[2 * jr * 2]; pa.u[1] = W[2 * jr * 2 + 1];
                   pa.u[2] = rA;            pa.u[3] = rB; }
        else     { pa.u[0] = rA;            pa.u[1] = rB;
                   pa.u[2] = W[(2 * jr + 1) * 2]; pa.u[3] = W[(2 * jr + 1) * 2 + 1]; }
        int j = s * 2 + jr;
        __builtin_amdgcn_s_setprio(1);
        bf16x8 vf0 = *(const bf16x8*)(Vp + (l31)*128 + (((2 * j + hi) ^ x7) << 4));
        ctx0 = __builtin_amdgcn_mfma_f32_32x32x16_bf16(pa.v, vf0, ctx0, 0, 0, 0);
        bf16x8 vf1 = *(const bf16x8*)(Vp + (32 + l31) * 128 + (((2 * j + hi) ^ x7) << 4));
        ctx1 = __builtin_amdgcn_mfma_f32_32x32x16_bf16(pa.v, vf1, ctx1, 0, 0, 0);
        __builtin_amdgcn_s_setprio(0);
      }
    }
  }

  // ---- finalize enc branch + write ------------------------------------------
  if (!hi) red[wave][l31] = lr;
  asm volatile("s_waitcnt lgkmcnt(0)" ::: "memory");
  float* op = out + ((size_t)b * SEQ) * HDIM + h * 64 + l31;
#pragma unroll
  for (int r2 = 0; r2 < 4; ++r2) {
    f4v lv = *(const f4v*)(&red[wave][r2 * 8 + 4 * hi]);
#pragma unroll
    for (int j2 = 0; j2 < 4; ++j2) {
      float li = __builtin_amdgcn_rcpf(lv[j2]);
      int s = qrow0 + r2 * 8 + 4 * hi + j2;
      int r = r2 * 4 + j2;
      op[(size_t)s * HDIM]      = 0.5f * (c10[r] + ctx0[r] * li);
      op[(size_t)s * HDIM + 32] = 0.5f * (c11[r] + ctx1[r] * li);
    }
  }
}

// ---- host launcher ---------------------------------------------------------
extern "C" void kernel_launch(void* const* d_in, const int* in_sizes, int n_in,
                              void* d_out, int out_size, void* d_ws, size_t ws_size,
                              hipStream_t stream) {
  const float* hid = (const float*)d_in[0];
  const float* enc = (const float*)d_in[1];
  const float* amask = (const float*)d_in[2];
  const float* emask = (const float*)d_in[3];

  char* ws = (char*)d_ws;
  short* hbf = (short*)(ws);                        // 8 MB  [B*S,H] bf16
  short* ebf = (short*)(ws + (8u << 20));           // 4 MB  [B*K,H]
  short* wt = (short*)(ws + (12u << 20));           // 12 MB 6x [n][k]
  short* qo = (short*)(ws + (24u << 20));           // 8 MB  [B,NH,S,HD]
  short* ko = (short*)(ws + (32u << 20));           // 8 MB
  short* vT = (short*)(ws + (40u << 20));           // 8 MB  [B,NH,HD,S]
  short* kqo = (short*)(ws + (48u << 20));          // 8 MB
  short* kko = (short*)(ws + (56u << 20));          // 4 MB  [B,NH,K,HD]
  short* kvT = (short*)(ws + (60u << 20));          // 4 MB  [B,NH,HD,K]

  cast_bf16<<<4096, 256, 0, stream>>>(hid, hbf, (BATCH * SEQ * HDIM) / 4);
  cast_bf16<<<2048, 256, 0, stream>>>(enc, ebf, (BATCH * KENC * HDIM) / 4);

  WtArgs wa;
  for (int j = 0; j < 6; ++j) wa.W[j] = (const float*)d_in[4 + 2 * j];
  wt_cast<<<dim3(32, 32, 6), 256, 0, stream>>>(wa, wt);

  ProjArgs pa;
  const short* Xs[6] = {hbf, hbf, hbf, hbf, ebf, ebf};
  short* outs[6] = {qo, ko, vT, kqo, kko, kvT};
  const int Ms[6] = {4096, 4096, 4096, 4096, 2048, 2048};
  const int tsh[6] = {10, 10, 10, 10, 9, 9};
  const int md[6] = {0, 0, 1, 0, 0, 1};
  const float qscale = 0.125f * LOG2E;
  const float scl[6] = {qscale, 1.f, 1.f, qscale, 1.f, 1.f};
  for (int j = 0; j < 6; ++j) {
    pa.X[j] = Xs[j];
    pa.Wt[j] = wt + (size_t)j * (HDIM * HDIM);
    pa.bias[j] = (const float*)d_in[5 + 2 * j];
    pa.out[j] = outs[j];
    pa.M[j] = Ms[j];
    pa.tshift[j] = tsh[j];
    pa.mode[j] = md[j];
    pa.scale[j] = scl[j];
  }
  proj_gemm<<<dim3(8, 32, 6), 256, 0, stream>>>(pa);

  attn32<<<512, 256, 0, stream>>>(qo, ko, vT, kqo, kko, kvT, amask, emask,
                                  (float*)d_out);
}

// Round 5
// 147.444 us; speedup vs baseline: 1.1716x; 1.0013x over previous
//
#include <hip/hip_runtime.h>

// ---- constants -------------------------------------------------------------
#define BATCH 4
#define SEQ   1024
#define KENC  512
#define HDIM  1024
#define NHEAD 16
#define HD    64
#define LOG2E 1.44269504088896340736f

typedef __attribute__((ext_vector_type(8))) short bf16x8;
typedef __attribute__((ext_vector_type(4))) float f32x4;
typedef __attribute__((ext_vector_type(16))) float f32x16;
typedef __attribute__((ext_vector_type(4))) float f4v;
typedef __attribute__((ext_vector_type(4))) short s4v;

__device__ __forceinline__ short f2bf(float f) {
  unsigned u = __float_as_uint(f);
  u += 0x7fffu + ((u >> 16) & 1u);   // RNE
  return (short)(u >> 16);
}

__device__ __forceinline__ void gload_lds16(const void* g, void* l) {
  __builtin_amdgcn_global_load_lds(
      (const __attribute__((address_space(1))) void*)g,
      (__attribute__((address_space(3))) void*)l, 16, 0, 0);
}

// ---- kernel 1: f32 -> bf16 cast (vectorized) -------------------------------
__global__ __launch_bounds__(256) void cast_bf16(const float* __restrict__ src,
                                                 short* __restrict__ dst, int n4) {
  int i = blockIdx.x * 256 + threadIdx.x;
  if (i >= n4) return;
  f4v v = ((const f4v*)src)[i];
  s4v o;
#pragma unroll
  for (int j = 0; j < 4; ++j) o[j] = f2bf(v[j]);
  ((s4v*)dst)[i] = o;
}

// ---- kernel 2: weight cast + transpose: Wt[n][k] = W[k][n] -----------------
struct WtArgs { const float* W[6]; };

__global__ __launch_bounds__(256) void wt_cast(WtArgs a, short* __restrict__ wt) {
  int j = blockIdx.z;
  const float* W = a.W[j];
  short* dst = wt + (size_t)j * (HDIM * HDIM);
  int cb = blockIdx.x * 32, rb = blockIdx.y * 32;
  __shared__ float t[32][33];
  int tx = threadIdx.x & 31, ty = threadIdx.x >> 5;
#pragma unroll
  for (int rr = 0; rr < 4; ++rr)
    t[ty + rr * 8][tx] = W[(size_t)(rb + ty + rr * 8) * HDIM + cb + tx];
  __syncthreads();
#pragma unroll
  for (int rr = 0; rr < 4; ++rr)
    dst[(size_t)(cb + ty + rr * 8) * HDIM + rb + tx] = f2bf(t[tx][ty + rr * 8]);
}

// ---- kernel 3: projection GEMM, 128x128 tile, BK=32, QUAD-buffer -----------
// Counted-vmcnt deep pipeline (T4): stage tile t+3 while computing tile t;
// one s_barrier per K-step preceded by s_waitcnt vmcnt(8) (loads issued two
// compute-steps earlier). 64 KB LDS -> 2 blocks/CU.
struct ProjArgs {
  const short* X[6];
  const short* Wt[6];
  const float* bias[6];
  short* out[6];
  int M[6];
  int tshift[6];  // log2(tokens): 10 or 9
  int mode[6];    // 0 std, 1 transposed
  float scale[6]; // epilogue scale (0.125*log2e for q/kq)
};

__global__ __launch_bounds__(256) void proj_gemm(ProjArgs a) {
  int job = blockIdx.z;
  int M = a.M[job];
  int by = blockIdx.y;
  if (by * 128 >= M) return;
  int bx = blockIdx.x;
  const short* X = a.X[job];
  const short* W = a.Wt[job];

  __shared__ __align__(16) char Lds[4][16384];   // per buf: A 8K | B 8K

  int tid = threadIdx.x, lane = tid & 63, wave = tid >> 6;
  int wr = wave >> 1, wc = wave & 1;
  int l15 = lane & 15, g4 = lane >> 4;

  f32x4 acc[4][4];
#pragma unroll
  for (int m = 0; m < 4; ++m)
#pragma unroll
    for (int n = 0; n < 4; ++n)
#pragma unroll
      for (int r = 0; r < 4; ++r) acc[m][n][r] = 0.0f;

  int arow = by * 128, brow = bx * 128;
  // staging: chunk c = wave*2+cc covers 16 rows; lane -> row 16c+(l>>2),
  // phys 16B-slot lane&3, source slot pre-swizzled (involution).
  const int crow = lane >> 2;
  const int sgrp = (lane & 3) ^ ((lane >> 2) & 3) ^ (lane >> 4);
  const int rsw = (lane & 3) ^ (l15 >> 2);

  const short* Xb = X + (size_t)arow * HDIM + (size_t)crow * HDIM + sgrp * 8;
  const short* Wb = W + (size_t)brow * HDIM + (size_t)crow * HDIM + sgrp * 8;

#define STAGE(buf, kt)                                                        \
  do {                                                                        \
    _Pragma("unroll") for (int cc = 0; cc < 2; ++cc) {                        \
      int c = wave * 2 + cc;                                                  \
      gload_lds16(Xb + (size_t)c * 16 * HDIM + (kt) * 32,                     \
                  (char*)Lds[buf] + c * 1024 + lane * 16);                    \
      gload_lds16(Wb + (size_t)c * 16 * HDIM + (kt) * 32,                     \
                  (char*)Lds[buf] + 8192 + c * 1024 + lane * 16);             \
    }                                                                         \
  } while (0)

  // NOTE: gload_lds dest is wave-uniform base + lane*16 -> pass base only.
  // (lane*16 term in macro is folded out by the builtin's addressing; keep
  // the layout identical to source order.)

  int aoff = (wr * 64 + l15) * 64 + ((g4 ^ rsw) << 4);
  int boff = 8192 + (wc * 64 + l15) * 64 + ((g4 ^ rsw) << 4);

  // prologue: stage tiles 0,1,2 -> bufs 0,1,2 (12 gloads); wait tile 0.
  STAGE(0, 0);
  STAGE(1, 1);
  STAGE(2, 2);
  asm volatile("s_waitcnt vmcnt(8)" ::: "memory");
  __builtin_amdgcn_s_barrier();
  asm volatile("" ::: "memory");

  bf16x8 af[4], bfr[4];

#define STEP(BUF, DO_STG, SBUF, SKT, WAITN, DO_BAR)                           \
  do {                                                                        \
    _Pragma("unroll") for (int m = 0; m < 4; ++m)                             \
        af[m] = *(const bf16x8*)((const char*)Lds[BUF] + m * 1024 + aoff);    \
    _Pragma("unroll") for (int n = 0; n < 4; ++n)                             \
        bfr[n] = *(const bf16x8*)((const char*)Lds[BUF] + n * 1024 + boff);   \
    if (DO_STG) STAGE(SBUF, SKT);                                             \
    __builtin_amdgcn_s_setprio(1);                                            \
    _Pragma("unroll") for (int m = 0; m < 4; ++m)                             \
        _Pragma("unroll") for (int n = 0; n < 4; ++n)                         \
            acc[m][n] = __builtin_amdgcn_mfma_f32_16x16x32_bf16(              \
                af[m], bfr[n], acc[m][n], 0, 0, 0);                           \
    __builtin_amdgcn_s_setprio(0);                                            \
    if (WAITN >= 0) {                                                         \
      if (WAITN == 8) asm volatile("s_waitcnt vmcnt(8)" ::: "memory");        \
      else if (WAITN == 4) asm volatile("s_waitcnt vmcnt(4)" ::: "memory");   \
      else asm volatile("s_waitcnt vmcnt(0)" ::: "memory");                   \
    }                                                                         \
    if (DO_BAR) {                                                             \
      __builtin_amdgcn_s_barrier();                                           \
      asm volatile("" ::: "memory");                                          \
    }                                                                         \
  } while (0)

#pragma unroll 1
  for (int t = 0; t < 28; t += 4) {
    STEP(0, 1, 3, t + 3, 8, 1);
    STEP(1, 1, 0, t + 4, 8, 1);
    STEP(2, 1, 1, t + 5, 8, 1);
    STEP(3, 1, 2, t + 6, 8, 1);
  }
  STEP(0, 1, 3, 31, 8, 1);   // t=28 stages tile 31
  STEP(1, 0, 0, 0, 4, 1);    // t=29
  STEP(2, 0, 0, 0, 0, 1);    // t=30
  STEP(3, 0, 0, 0, -1, 0);   // t=31

#undef STEP
#undef STAGE

  const float* bias = a.bias[job];
  short* out = a.out[job];
  int tshift = a.tshift[job], tmask = (1 << tshift) - 1, mode = a.mode[job];
  float scl = a.scale[job];
#pragma unroll
  for (int m = 0; m < 4; ++m) {
    int rowb = arow + wr * 64 + m * 16 + (g4 << 2);
#pragma unroll
    for (int n = 0; n < 4; ++n) {
      int col = brow + wc * 64 + n * 16 + l15;
      float bv = bias[col];
      int head = col >> 6, d = col & 63;
#pragma unroll
      for (int r = 0; r < 4; ++r) {
        int row = rowb + r;
        int bb = row >> tshift, t = row & tmask;
        float val = (acc[m][n][r] + bv) * scl;
        size_t idx;
        if (mode == 0)
          idx = ((((size_t)bb * NHEAD + head) << tshift) + t) * 64 + d;
        else
          idx = ((((size_t)bb * NHEAD + head) * 64 + d) << tshift) + t;
        out[idx] = f2bf(val);
      }
    }
  }
}

// ---- kernel 4: swapped-QK^T 32x32 flash attention --------------------------
__global__ __launch_bounds__(256, 3) void attn32(
    const short* __restrict__ qall, const short* __restrict__ kall,
    const short* __restrict__ vTall, const short* __restrict__ kqall,
    const short* __restrict__ kkall, const short* __restrict__ kvTall,
    const float* __restrict__ amask, const float* __restrict__ emask,
    float* __restrict__ out) {
  __shared__ char KT[2][8192];
  __shared__ char VT[2][8192];
  __shared__ float red[4][32];

  int lid = blockIdx.x;
  int id = (lid & 7) * 64 + (lid >> 3);
  int bh = id >> 3, qb = id & 7;
  int b = bh >> 4, h = bh & 15;
  int lane = threadIdx.x & 63, wave = threadIdx.x >> 6;
  int l31 = lane & 31, hi = lane >> 5, x7 = l31 & 7;
  int qrow0 = qb * 128 + wave * 32;

  bf16x8 qcur[4];
  {
    const short* qp = qall + ((size_t)bh * SEQ + qrow0 + l31) * 64;
#pragma unroll
    for (int i = 0; i < 4; ++i)
      qcur[i] = *(const bf16x8*)(qp + i * 16 + hi * 8);
  }

  const char* kb0 = (const char*)(kall + (size_t)bh * SEQ * 64);
  const char* vb0 = (const char*)(vTall + (size_t)bh * 64 * SEQ);
  const char* kb1 = (const char*)(kkall + (size_t)bh * KENC * 64);
  const char* vb1 = (const char*)(kvTall + (size_t)bh * 64 * KENC);
  const float* mpc = amask + (size_t)b * SEQ;

  auto STAGE = [&](int pb, const char* kb, const char* vb, size_t vrowb, int kt) {
    int t0 = threadIdx.x;
#pragma unroll
    for (int c = 0; c < 2; ++c) {
      int idx = c * 256 + t0;
      int row = idx >> 3, phys = idx & 7;
      int lg = phys ^ (row & 7);
      gload_lds16(kb + ((size_t)(kt * 64 + row)) * 128 + lg * 16,
                  KT[pb] + idx * 16);
      gload_lds16(vb + (size_t)row * vrowb + (size_t)kt * 128 + lg * 16,
                  VT[pb] + idx * 16);
    }
  };

  STAGE(0, kb0, vb0, SEQ * 2, 0);

  f32x16 ctx0, ctx1, c10, c11;
#pragma unroll
  for (int r = 0; r < 16; ++r) { ctx0[r] = 0.f; ctx1[r] = 0.f; c10[r] = 0.f; c11[r] = 0.f; }
  float mr = -1e30f, lr = 0.f;

#pragma unroll 1
  for (int t = 0; t < 24; ++t) {
    int p = t & 1;
    __syncthreads();
    if (t < 23) {
      int tn = t + 1;
      if (tn >= 16) STAGE(p ^ 1, kb1, vb1, KENC * 2, tn - 16);
      else          STAGE(p ^ 1, kb0, vb0, SEQ * 2, tn);
    }
    if (t == 16) {
      if (!hi) red[wave][l31] = lr;
      asm volatile("s_waitcnt lgkmcnt(0)" ::: "memory");
#pragma unroll
      for (int r2 = 0; r2 < 4; ++r2) {
        f4v lv = *(const f4v*)(&red[wave][r2 * 8 + 4 * hi]);
#pragma unroll
        for (int j2 = 0; j2 < 4; ++j2) {
          float li = __builtin_amdgcn_rcpf(lv[j2]);
          int r = r2 * 4 + j2;
          c10[r] = ctx0[r] * li;  ctx0[r] = 0.f;
          c11[r] = ctx1[r] * li;  ctx1[r] = 0.f;
        }
      }
      mr = -1e30f; lr = 0.f;
      const short* kqp = kqall + ((size_t)bh * SEQ + qrow0 + l31) * 64;
#pragma unroll
      for (int i = 0; i < 4; ++i)
        qcur[i] = *(const bf16x8*)(kqp + i * 16 + hi * 8);
      mpc = emask + (size_t)b * KENC;
    }
    int kt = (t >= 16) ? t - 16 : t;
    const char* Kp = KT[p];
    const char* Vp = VT[p];

    f32x16 s0, s1;
#pragma unroll
    for (int r = 0; r < 16; ++r) { s0[r] = 0.f; s1[r] = 0.f; }
    __builtin_amdgcn_s_setprio(1);
#pragma unroll
    for (int i = 0; i < 4; ++i) {
      bf16x8 kf = *(const bf16x8*)(Kp + (l31)*128 + (((2 * i + hi) ^ x7) << 4));
      s0 = __builtin_amdgcn_mfma_f32_32x32x16_bf16(kf, qcur[i], s0, 0, 0, 0);
    }
#pragma unroll
    for (int i = 0; i < 4; ++i) {
      bf16x8 kf = *(const bf16x8*)(Kp + (32 + l31) * 128 + (((2 * i + hi) ^ x7) << 4));
      s1 = __builtin_amdgcn_mfma_f32_32x32x16_bf16(kf, qcur[i], s1, 0, 0, 0);
    }
    __builtin_amdgcn_s_setprio(0);

    const float* mp = mpc + kt * 64;
#pragma unroll
    for (int r2 = 0; r2 < 4; ++r2) {
      f4v ma = *(const f4v*)(mp + r2 * 8 + 4 * hi);
      f4v mb = *(const f4v*)(mp + 32 + r2 * 8 + 4 * hi);
#pragma unroll
      for (int j2 = 0; j2 < 4; ++j2) {
        s0[r2 * 4 + j2] = fmaf(ma[j2], LOG2E, s0[r2 * 4 + j2]);
        s1[r2 * 4 + j2] = fmaf(mb[j2], LOG2E, s1[r2 * 4 + j2]);
      }
    }

    float mx = s0[0];
#pragma unroll
    for (int r = 1; r < 16; ++r) mx = fmaxf(mx, s0[r]);
#pragma unroll
    for (int r = 0; r < 16; ++r) mx = fmaxf(mx, s1[r]);
    mx = fmaxf(mx, __int_as_float(__shfl_xor(__float_as_int(mx), 32)));

    if (!__all(mx <= mr + 12.f)) {
      float mn = fmaxf(mr, mx);
      float scl = __builtin_amdgcn_exp2f(mr - mn);
      mr = mn; lr *= scl;
      if (!hi) red[wave][l31] = scl;
      asm volatile("s_waitcnt lgkmcnt(0)" ::: "memory");
#pragma unroll
      for (int r2 = 0; r2 < 4; ++r2) {
        f4v sv = *(const f4v*)(&red[wave][r2 * 8 + 4 * hi]);
#pragma unroll
        for (int j2 = 0; j2 < 4; ++j2) {
          ctx0[r2 * 4 + j2] *= sv[j2];
          ctx1[r2 * 4 + j2] *= sv[j2];
        }
      }
    }

    float rs = 0.f;
#pragma unroll
    for (int r = 0; r < 16; ++r) { s0[r] = __builtin_amdgcn_exp2f(s0[r] - mr); rs += s0[r]; }
#pragma unroll
    for (int r = 0; r < 16; ++r) { s1[r] = __builtin_amdgcn_exp2f(s1[r] - mr); rs += s1[r]; }
    rs += __int_as_float(__shfl_xor(__float_as_int(rs), 32));
    lr += rs;

#pragma unroll
    for (int s = 0; s < 2; ++s) {
      const f32x16& sv = s ? s1 : s0;
      unsigned W[8];
#pragma unroll
      for (int r2 = 0; r2 < 4; ++r2) {
        asm("v_cvt_pk_bf16_f32 %0, %1, %2"
            : "=v"(W[r2 * 2]) : "v"(sv[r2 * 4 + 0]), "v"(sv[r2 * 4 + 1]));
        asm("v_cvt_pk_bf16_f32 %0, %1, %2"
            : "=v"(W[r2 * 2 + 1]) : "v"(sv[r2 * 4 + 2]), "v"(sv[r2 * 4 + 3]));
      }
#pragma unroll
      for (int jr = 0; jr < 2; ++jr) {
        unsigned sendA = hi ? W[(2 * jr) * 2]     : W[(2 * jr + 1) * 2];
        unsigned sendB = hi ? W[(2 * jr) * 2 + 1] : W[(2 * jr + 1) * 2 + 1];
        unsigned rA = (unsigned)__shfl_xor((int)sendA, 32);
        unsigned rB = (unsigned)__shfl_xor((int)sendB, 32);
        union { unsigned u[4]; bf16x8 v; } pa;
        if (!hi) { pa.u[0] = W[2 * jr * 2]; pa.u[1] = W[2 * jr * 2 + 1];
                   pa.u[2] = rA;            pa.u[3] = rB; }
        else     { pa.u[0] = rA;            pa.u[1] = rB;
                   pa.u[2] = W[(2 * jr + 1) * 2]; pa.u[3] = W[(2 * jr + 1) * 2 + 1]; }
        int j = s * 2 + jr;
        __builtin_amdgcn_s_setprio(1);
        bf16x8 vf0 = *(const bf16x8*)(Vp + (l31)*128 + (((2 * j + hi) ^ x7) << 4));
        ctx0 = __builtin_amdgcn_mfma_f32_32x32x16_bf16(pa.v, vf0, ctx0, 0, 0, 0);
        bf16x8 vf1 = *(const bf16x8*)(Vp + (32 + l31) * 128 + (((2 * j + hi) ^ x7) << 4));
        ctx1 = __builtin_amdgcn_mfma_f32_32x32x16_bf16(pa.v, vf1, ctx1, 0, 0, 0);
        __builtin_amdgcn_s_setprio(0);
      }
    }
  }

  if (!hi) red[wave][l31] = lr;
  asm volatile("s_waitcnt lgkmcnt(0)" ::: "memory");
  float* op = out + ((size_t)b * SEQ) * HDIM + h * 64 + l31;
#pragma unroll
  for (int r2 = 0; r2 < 4; ++r2) {
    f4v lv = *(const f4v*)(&red[wave][r2 * 8 + 4 * hi]);
#pragma unroll
    for (int j2 = 0; j2 < 4; ++j2) {
      float li = __builtin_amdgcn_rcpf(lv[j2]);
      int s = qrow0 + r2 * 8 + 4 * hi + j2;
      int r = r2 * 4 + j2;
      op[(size_t)s * HDIM]      = 0.5f * (c10[r] + ctx0[r] * li);
      op[(size_t)s * HDIM + 32] = 0.5f * (c11[r] + ctx1[r] * li);
    }
  }
}

// ---- host launcher ---------------------------------------------------------
extern "C" void kernel_launch(void* const* d_in, const int* in_sizes, int n_in,
                              void* d_out, int out_size, void* d_ws, size_t ws_size,
                              hipStream_t stream) {
  const float* hid = (const float*)d_in[0];
  const float* enc = (const float*)d_in[1];
  const float* amask = (const float*)d_in[2];
  const float* emask = (const float*)d_in[3];

  char* ws = (char*)d_ws;
  short* hbf = (short*)(ws);                        // 8 MB  [B*S,H] bf16
  short* ebf = (short*)(ws + (8u << 20));           // 4 MB  [B*K,H]
  short* wt = (short*)(ws + (12u << 20));           // 12 MB 6x [n][k]
  short* qo = (short*)(ws + (24u << 20));           // 8 MB  [B,NH,S,HD]
  short* ko = (short*)(ws + (32u << 20));           // 8 MB
  short* vT = (short*)(ws + (40u << 20));           // 8 MB  [B,NH,HD,S]
  short* kqo = (short*)(ws + (48u << 20));          // 8 MB
  short* kko = (short*)(ws + (56u << 20));          // 4 MB  [B,NH,K,HD]
  short* kvT = (short*)(ws + (60u << 20));          // 4 MB  [B,NH,HD,K]

  cast_bf16<<<4096, 256, 0, stream>>>(hid, hbf, (BATCH * SEQ * HDIM) / 4);
  cast_bf16<<<2048, 256, 0, stream>>>(enc, ebf, (BATCH * KENC * HDIM) / 4);

  WtArgs wa;
  for (int j = 0; j < 6; ++j) wa.W[j] = (const float*)d_in[4 + 2 * j];
  wt_cast<<<dim3(32, 32, 6), 256, 0, stream>>>(wa, wt);

  ProjArgs pa;
  const short* Xs[6] = {hbf, hbf, hbf, hbf, ebf, ebf};
  short* outs[6] = {qo, ko, vT, kqo, kko, kvT};
  const int Ms[6] = {4096, 4096, 4096, 4096, 2048, 2048};
  const int tsh[6] = {10, 10, 10, 10, 9, 9};
  const int md[6] = {0, 0, 1, 0, 0, 1};
  const float qscale = 0.125f * LOG2E;
  const float scl[6] = {qscale, 1.f, 1.f, qscale, 1.f, 1.f};
  for (int j = 0; j < 6; ++j) {
    pa.X[j] = Xs[j];
    pa.Wt[j] = wt + (size_t)j * (HDIM * HDIM);
    pa.bias[j] = (const float*)d_in[5 + 2 * j];
    pa.out[j] = outs[j];
    pa.M[j] = Ms[j];
    pa.tshift[j] = tsh[j];
    pa.mode[j] = md[j];
    pa.scale[j] = scl[j];
  }
  proj_gemm<<<dim3(8, 32, 6), 256, 0, stream>>>(pa);

  attn32<<<512, 256, 0, stream>>>(qo, ko, vT, kqo, kko, kvT, amask, emask,
                                  (float*)d_out);
}

// Round 7
// 146.621 us; speedup vs baseline: 1.1782x; 1.0056x over previous
//
#include <hip/hip_runtime.h>

// ---- constants -------------------------------------------------------------
#define BATCH 4
#define SEQ   1024
#define KENC  512
#define HDIM  1024
#define NHEAD 16
#define HD    64
#define LOG2E 1.44269504088896340736f

typedef __attribute__((ext_vector_type(8))) short bf16x8;
typedef __attribute__((ext_vector_type(4))) float f32x4;
typedef __attribute__((ext_vector_type(16))) float f32x16;
typedef __attribute__((ext_vector_type(4))) float f4v;
typedef __attribute__((ext_vector_type(4))) short s4v;

__device__ __forceinline__ short f2bf(float f) {
  unsigned u = __float_as_uint(f);
  u += 0x7fffu + ((u >> 16) & 1u);   // RNE
  return (short)(u >> 16);
}

__device__ __forceinline__ void gload_lds16(const void* g, void* l) {
  __builtin_amdgcn_global_load_lds(
      (const __attribute__((address_space(1))) void*)g,
      (__attribute__((address_space(3))) void*)l, 16, 0, 0);
}

#define MF(A, B, C) __builtin_amdgcn_mfma_f32_16x16x32_bf16((A), (B), (C), 0, 0, 0)

// ---- kernel 1: f32 -> bf16 cast (vectorized) -------------------------------
__global__ __launch_bounds__(256) void cast_bf16(const float* __restrict__ src,
                                                 short* __restrict__ dst, int n4) {
  int i = blockIdx.x * 256 + threadIdx.x;
  if (i >= n4) return;
  f4v v = ((const f4v*)src)[i];
  s4v o;
#pragma unroll
  for (int j = 0; j < 4; ++j) o[j] = f2bf(v[j]);
  ((s4v*)dst)[i] = o;
}

// ---- kernel 2: weight cast + transpose: Wt[n][k] = W[k][n] -----------------
struct WtArgs { const float* W[6]; };

__global__ __launch_bounds__(256) void wt_cast(WtArgs a, short* __restrict__ wt) {
  int j = blockIdx.z;
  const float* W = a.W[j];
  short* dst = wt + (size_t)j * (HDIM * HDIM);
  int cb = blockIdx.x * 32, rb = blockIdx.y * 32;
  __shared__ float t[32][33];
  int tx = threadIdx.x & 31, ty = threadIdx.x >> 5;
#pragma unroll
  for (int rr = 0; rr < 4; ++rr)
    t[ty + rr * 8][tx] = W[(size_t)(rb + ty + rr * 8) * HDIM + cb + tx];
  __syncthreads();
#pragma unroll
  for (int rr = 0; rr < 4; ++rr)
    dst[(size_t)(cb + ty + rr * 8) * HDIM + rb + tx] = f2bf(t[tx][ty + rr * 8]);
}

// ---- kernel 3: projection GEMM, 128x128 tile, BK=32, quad-buffer -----------
// Fine-interleaved 2-phase K-step: frag ds_reads issued ONE PHASE EARLY so
// MFMAs never wait on fresh LDS reads; stage gloads interleaved between MFMA
// clusters; single barrier + counted vmcnt(4) per K-step.
struct ProjArgs {
  const short* X[6];
  const short* Wt[6];
  const float* bias[6];
  short* out[6];
  int M[6];
  int tshift[6];  // log2(tokens): 10 or 9
  int mode[6];    // 0 std, 1 transposed
  float scale[6]; // epilogue scale (0.125*log2e for q/kq)
};

__global__ __launch_bounds__(256) void proj_gemm(ProjArgs a) {
  int job = blockIdx.z;
  int M = a.M[job];
  int by = blockIdx.y;
  if (by * 128 >= M) return;
  int bx = blockIdx.x;
  const short* X = a.X[job];
  const short* W = a.Wt[job];

  __shared__ __align__(16) char Lds[65536];   // 4 bufs x (A 8K | B 8K)

  int tid = threadIdx.x, lane = tid & 63, wave = tid >> 6;
  int wr = wave >> 1, wc = wave & 1;
  int l15 = lane & 15, g4 = lane >> 4;

  f32x4 acc[4][4];
#pragma unroll
  for (int m = 0; m < 4; ++m)
#pragma unroll
    for (int n = 0; n < 4; ++n)
#pragma unroll
      for (int r = 0; r < 4; ++r) acc[m][n][r] = 0.0f;

  int arow = by * 128, brow = bx * 128;
  const int crow = lane >> 2;
  const int sgrp = (lane & 3) ^ ((lane >> 2) & 3) ^ (lane >> 4);
  const int rsw = (lane & 3) ^ (l15 >> 2);

  const char* Xb = (const char*)X;
  const char* Wb = (const char*)W;
  const size_t sac0 = ((size_t)(arow + 32 * wave + crow) * HDIM + sgrp * 8) * 2;
  const size_t sac1 = sac0 + (size_t)16 * HDIM * 2;
  const size_t sbc0 = ((size_t)(brow + 32 * wave + crow) * HDIM + sgrp * 8) * 2;
  const size_t sbc1 = sbc0 + (size_t)16 * HDIM * 2;
  const int ldA0 = wave * 2048, ldA1 = ldA0 + 1024;
  const int ldB0 = 8192 + ldA0, ldB1 = ldB0 + 1024;

  const int aoff = wr * 4096 + l15 * 64 + ((g4 ^ rsw) << 4);
  const int boff = 8192 + wc * 4096 + l15 * 64 + ((g4 ^ rsw) << 4);

#define STG_A(SBO, SKT)                                                  \
  do {                                                                   \
    gload_lds16(Xb + sac0 + (size_t)(SKT) * 64, Lds + (SBO) + ldA0);     \
    gload_lds16(Xb + sac1 + (size_t)(SKT) * 64, Lds + (SBO) + ldA1);     \
  } while (0)
#define STG_B(SBO, SKT)                                                  \
  do {                                                                   \
    gload_lds16(Wb + sbc0 + (size_t)(SKT) * 64, Lds + (SBO) + ldB0);     \
    gload_lds16(Wb + sbc1 + (size_t)(SKT) * 64, Lds + (SBO) + ldB1);     \
  } while (0)

  // prologue: tiles 0,1,2 -> bufs 0,1,2; publish tiles 0,1.
  STG_A(0, 0);     STG_B(0, 0);
  STG_A(16384, 1); STG_B(16384, 1);
  STG_A(32768, 2); STG_B(32768, 2);
  asm volatile("s_waitcnt vmcnt(4)" ::: "memory");
  __builtin_amdgcn_s_barrier();
  asm volatile("" ::: "memory");

  // ping-pong frag sets (static names; rule #20)
  bf16x8 xa0, xa1, xb0, xb1, xb2, xb3;
  bf16x8 ya0, ya1, yb0, yb1, yb2, yb3;

  // preload quad-A + B of buf0 (tile 0) into X set
  xa0 = *(const bf16x8*)(Lds + 0 * 1024 + aoff);
  xa1 = *(const bf16x8*)(Lds + 1 * 1024 + aoff);
  xb0 = *(const bf16x8*)(Lds + 0 * 1024 + boff);
  xb1 = *(const bf16x8*)(Lds + 1 * 1024 + boff);
  xb2 = *(const bf16x8*)(Lds + 2 * 1024 + boff);
  xb3 = *(const bf16x8*)(Lds + 3 * 1024 + boff);

// One K-step. CUR frags were loaded last step (already landed); quad-B A-frags
// (q2,q3) read at step start overlap quad-A MFMAs; NXT frag reads overlap
// quad-B MFMAs. Counted vmcnt + single barrier at step end.
// NOTE the GSTEP(...) -> GSTEP_I indirection: lets XSET/YSET (object-like
// macros) expand into 6 arguments each before GSTEP_I's parameter matching.
#define GSTEP_I(BO, BON, CA0, CA1, CB0, CB1, CB2, CB3, NA0, NA1, NB0, NB1,    \
                NB2, NB3, DO_STG, SBO, SKT, DO_NEXT, VMASM, DO_BAR)           \
  do {                                                                        \
    bf16x8 q2 = *(const bf16x8*)(Lds + (BO) + 2 * 1024 + aoff);               \
    bf16x8 q3 = *(const bf16x8*)(Lds + (BO) + 3 * 1024 + aoff);               \
    if (DO_STG) STG_A(SBO, SKT);                                              \
    __builtin_amdgcn_s_setprio(1);                                            \
    acc[0][0] = MF(CA0, CB0, acc[0][0]);                                      \
    acc[0][1] = MF(CA0, CB1, acc[0][1]);                                      \
    acc[0][2] = MF(CA0, CB2, acc[0][2]);                                      \
    acc[0][3] = MF(CA0, CB3, acc[0][3]);                                      \
    acc[1][0] = MF(CA1, CB0, acc[1][0]);                                      \
    acc[1][1] = MF(CA1, CB1, acc[1][1]);                                      \
    acc[1][2] = MF(CA1, CB2, acc[1][2]);                                      \
    acc[1][3] = MF(CA1, CB3, acc[1][3]);                                      \
    __builtin_amdgcn_s_setprio(0);                                            \
    if (DO_NEXT) {                                                            \
      NA0 = *(const bf16x8*)(Lds + (BON) + 0 * 1024 + aoff);                  \
      NA1 = *(const bf16x8*)(Lds + (BON) + 1 * 1024 + aoff);                  \
      NB0 = *(const bf16x8*)(Lds + (BON) + 0 * 1024 + boff);                  \
      NB1 = *(const bf16x8*)(Lds + (BON) + 1 * 1024 + boff);                  \
      NB2 = *(const bf16x8*)(Lds + (BON) + 2 * 1024 + boff);                  \
      NB3 = *(const bf16x8*)(Lds + (BON) + 3 * 1024 + boff);                  \
    }                                                                         \
    if (DO_STG) STG_B(SBO, SKT);                                              \
    __builtin_amdgcn_s_setprio(1);                                            \
    acc[2][0] = MF(q2, CB0, acc[2][0]);                                       \
    acc[2][1] = MF(q2, CB1, acc[2][1]);                                       \
    acc[2][2] = MF(q2, CB2, acc[2][2]);                                       \
    acc[2][3] = MF(q2, CB3, acc[2][3]);                                       \
    acc[3][0] = MF(q3, CB0, acc[3][0]);                                       \
    acc[3][1] = MF(q3, CB1, acc[3][1]);                                       \
    acc[3][2] = MF(q3, CB2, acc[3][2]);                                       \
    acc[3][3] = MF(q3, CB3, acc[3][3]);                                       \
    __builtin_amdgcn_s_setprio(0);                                            \
    asm volatile(VMASM ::: "memory");                                         \
    if (DO_BAR) {                                                             \
      __builtin_amdgcn_s_barrier();                                           \
      asm volatile("" ::: "memory");                                          \
    }                                                                         \
  } while (0)
#define GSTEP(...) GSTEP_I(__VA_ARGS__)

#define XSET xa0, xa1, xb0, xb1, xb2, xb3
#define YSET ya0, ya1, yb0, yb1, yb2, yb3

#pragma unroll 1
  for (int it = 0; it < 7; ++it) {
    int t0 = it * 4;
    GSTEP(0,     16384, XSET, YSET, 1, 49152, t0 + 3, 1, "s_waitcnt vmcnt(4)", 1);
    GSTEP(16384, 32768, YSET, XSET, 1, 0,     t0 + 4, 1, "s_waitcnt vmcnt(4)", 1);
    GSTEP(32768, 49152, XSET, YSET, 1, 16384, t0 + 5, 1, "s_waitcnt vmcnt(4)", 1);
    GSTEP(49152, 0,     YSET, XSET, 1, 32768, t0 + 6, 1, "s_waitcnt vmcnt(4)", 1);
  }
  // t=28 stages tile 31; t=29..31 drain
  GSTEP(0,     16384, XSET, YSET, 1, 49152, 31, 1, "s_waitcnt vmcnt(4)", 1);
  GSTEP(16384, 32768, YSET, XSET, 0, 0, 0,      1, "s_waitcnt vmcnt(0)", 1);
  GSTEP(32768, 49152, XSET, YSET, 0, 0, 0,      1, "s_nop 0", 1);
  GSTEP(49152, 0,     YSET, XSET, 0, 0, 0,      0, "s_nop 0", 0);

#undef GSTEP
#undef GSTEP_I
#undef XSET
#undef YSET
#undef STG_A
#undef STG_B

  const float* bias = a.bias[job];
  short* out = a.out[job];
  int tshift = a.tshift[job], tmask = (1 << tshift) - 1, mode = a.mode[job];
  float scl = a.scale[job];
#pragma unroll
  for (int m = 0; m < 4; ++m) {
    int rowb = arow + wr * 64 + m * 16 + (g4 << 2);
#pragma unroll
    for (int n = 0; n < 4; ++n) {
      int col = brow + wc * 64 + n * 16 + l15;
      float bv = bias[col];
      int head = col >> 6, d = col & 63;
#pragma unroll
      for (int r = 0; r < 4; ++r) {
        int row = rowb + r;
        int bb = row >> tshift, t = row & tmask;
        float val = (acc[m][n][r] + bv) * scl;
        size_t idx;
        if (mode == 0)
          idx = ((((size_t)bb * NHEAD + head) << tshift) + t) * 64 + d;
        else
          idx = ((((size_t)bb * NHEAD + head) * 64 + d) << tshift) + t;
        out[idx] = f2bf(val);
      }
    }
  }
}

// ---- kernel 4: swapped-QK^T 32x32 flash attention --------------------------
__global__ __launch_bounds__(256, 3) void attn32(
    const short* __restrict__ qall, const short* __restrict__ kall,
    const short* __restrict__ vTall, const short* __restrict__ kqall,
    const short* __restrict__ kkall, const short* __restrict__ kvTall,
    const float* __restrict__ amask, const float* __restrict__ emask,
    float* __restrict__ out) {
  __shared__ char KT[2][8192];
  __shared__ char VT[2][8192];
  __shared__ float red[4][32];

  int lid = blockIdx.x;
  int id = (lid & 7) * 64 + (lid >> 3);
  int bh = id >> 3, qb = id & 7;
  int b = bh >> 4, h = bh & 15;
  int lane = threadIdx.x & 63, wave = threadIdx.x >> 6;
  int l31 = lane & 31, hi = lane >> 5, x7 = l31 & 7;
  int qrow0 = qb * 128 + wave * 32;

  bf16x8 qcur[4];
  {
    const short* qp = qall + ((size_t)bh * SEQ + qrow0 + l31) * 64;
#pragma unroll
    for (int i = 0; i < 4; ++i)
      qcur[i] = *(const bf16x8*)(qp + i * 16 + hi * 8);
  }

  const char* kb0 = (const char*)(kall + (size_t)bh * SEQ * 64);
  const char* vb0 = (const char*)(vTall + (size_t)bh * 64 * SEQ);
  const char* kb1 = (const char*)(kkall + (size_t)bh * KENC * 64);
  const char* vb1 = (const char*)(kvTall + (size_t)bh * 64 * KENC);
  const float* mpc = amask + (size_t)b * SEQ;

  auto STAGE = [&](int pb, const char* kb, const char* vb, size_t vrowb, int kt) {
    int t0 = threadIdx.x;
#pragma unroll
    for (int c = 0; c < 2; ++c) {
      int idx = c * 256 + t0;
      int row = idx >> 3, phys = idx & 7;
      int lg = phys ^ (row & 7);
      gload_lds16(kb + ((size_t)(kt * 64 + row)) * 128 + lg * 16,
                  KT[pb] + idx * 16);
      gload_lds16(vb + (size_t)row * vrowb + (size_t)kt * 128 + lg * 16,
                  VT[pb] + idx * 16);
    }
  };

  STAGE(0, kb0, vb0, SEQ * 2, 0);

  f32x16 ctx0, ctx1, c10, c11;
#pragma unroll
  for (int r = 0; r < 16; ++r) { ctx0[r] = 0.f; ctx1[r] = 0.f; c10[r] = 0.f; c11[r] = 0.f; }
  float mr = -1e30f, lr = 0.f;

#pragma unroll 1
  for (int t = 0; t < 24; ++t) {
    int p = t & 1;
    __syncthreads();
    if (t < 23) {
      int tn = t + 1;
      if (tn >= 16) STAGE(p ^ 1, kb1, vb1, KENC * 2, tn - 16);
      else          STAGE(p ^ 1, kb0, vb0, SEQ * 2, tn);
    }
    if (t == 16) {
      if (!hi) red[wave][l31] = lr;
      asm volatile("s_waitcnt lgkmcnt(0)" ::: "memory");
#pragma unroll
      for (int r2 = 0; r2 < 4; ++r2) {
        f4v lv = *(const f4v*)(&red[wave][r2 * 8 + 4 * hi]);
#pragma unroll
        for (int j2 = 0; j2 < 4; ++j2) {
          float li = __builtin_amdgcn_rcpf(lv[j2]);
          int r = r2 * 4 + j2;
          c10[r] = ctx0[r] * li;  ctx0[r] = 0.f;
          c11[r] = ctx1[r] * li;  ctx1[r] = 0.f;
        }
      }
      mr = -1e30f; lr = 0.f;
      const short* kqp = kqall + ((size_t)bh * SEQ + qrow0 + l31) * 64;
#pragma unroll
      for (int i = 0; i < 4; ++i)
        qcur[i] = *(const bf16x8*)(kqp + i * 16 + hi * 8);
      mpc = emask + (size_t)b * KENC;
    }
    int kt = (t >= 16) ? t - 16 : t;
    const char* Kp = KT[p];
    const char* Vp = VT[p];

    f32x16 s0, s1;
#pragma unroll
    for (int r = 0; r < 16; ++r) { s0[r] = 0.f; s1[r] = 0.f; }
    __builtin_amdgcn_s_setprio(1);
#pragma unroll
    for (int i = 0; i < 4; ++i) {
      bf16x8 kf = *(const bf16x8*)(Kp + (l31)*128 + (((2 * i + hi) ^ x7) << 4));
      s0 = __builtin_amdgcn_mfma_f32_32x32x16_bf16(kf, qcur[i], s0, 0, 0, 0);
    }
#pragma unroll
    for (int i = 0; i < 4; ++i) {
      bf16x8 kf = *(const bf16x8*)(Kp + (32 + l31) * 128 + (((2 * i + hi) ^ x7) << 4));
      s1 = __builtin_amdgcn_mfma_f32_32x32x16_bf16(kf, qcur[i], s1, 0, 0, 0);
    }
    __builtin_amdgcn_s_setprio(0);

    const float* mp = mpc + kt * 64;
#pragma unroll
    for (int r2 = 0; r2 < 4; ++r2) {
      f4v ma = *(const f4v*)(mp + r2 * 8 + 4 * hi);
      f4v mb = *(const f4v*)(mp + 32 + r2 * 8 + 4 * hi);
#pragma unroll
      for (int j2 = 0; j2 < 4; ++j2) {
        s0[r2 * 4 + j2] = fmaf(ma[j2], LOG2E, s0[r2 * 4 + j2]);
        s1[r2 * 4 + j2] = fmaf(mb[j2], LOG2E, s1[r2 * 4 + j2]);
      }
    }

    float mx = s0[0];
#pragma unroll
    for (int r = 1; r < 16; ++r) mx = fmaxf(mx, s0[r]);
#pragma unroll
    for (int r = 0; r < 16; ++r) mx = fmaxf(mx, s1[r]);
    mx = fmaxf(mx, __int_as_float(__shfl_xor(__float_as_int(mx), 32)));

    if (!__all(mx <= mr + 12.f)) {
      float mn = fmaxf(mr, mx);
      float scl = __builtin_amdgcn_exp2f(mr - mn);
      mr = mn; lr *= scl;
      if (!hi) red[wave][l31] = scl;
      asm volatile("s_waitcnt lgkmcnt(0)" ::: "memory");
#pragma unroll
      for (int r2 = 0; r2 < 4; ++r2) {
        f4v sv = *(const f4v*)(&red[wave][r2 * 8 + 4 * hi]);
#pragma unroll
        for (int j2 = 0; j2 < 4; ++j2) {
          ctx0[r2 * 4 + j2] *= sv[j2];
          ctx1[r2 * 4 + j2] *= sv[j2];
        }
      }
    }

    float rs = 0.f;
#pragma unroll
    for (int r = 0; r < 16; ++r) { s0[r] = __builtin_amdgcn_exp2f(s0[r] - mr); rs += s0[r]; }
#pragma unroll
    for (int r = 0; r < 16; ++r) { s1[r] = __builtin_amdgcn_exp2f(s1[r] - mr); rs += s1[r]; }
    rs += __int_as_float(__shfl_xor(__float_as_int(rs), 32));
    lr += rs;

#pragma unroll
    for (int s = 0; s < 2; ++s) {
      const f32x16& sv = s ? s1 : s0;
      unsigned W[8];
#pragma unroll
      for (int r2 = 0; r2 < 4; ++r2) {
        asm("v_cvt_pk_bf16_f32 %0, %1, %2"
            : "=v"(W[r2 * 2]) : "v"(sv[r2 * 4 + 0]), "v"(sv[r2 * 4 + 1]));
        asm("v_cvt_pk_bf16_f32 %0, %1, %2"
            : "=v"(W[r2 * 2 + 1]) : "v"(sv[r2 * 4 + 2]), "v"(sv[r2 * 4 + 3]));
      }
#pragma unroll
      for (int jr = 0; jr < 2; ++jr) {
        unsigned sendA = hi ? W[(2 * jr) * 2]     : W[(2 * jr + 1) * 2];
        unsigned sendB = hi ? W[(2 * jr) * 2 + 1] : W[(2 * jr + 1) * 2 + 1];
        unsigned rA = (unsigned)__shfl_xor((int)sendA, 32);
        unsigned rB = (unsigned)__shfl_xor((int)sendB, 32);
        union { unsigned u[4]; bf16x8 v; } pa;
        if (!hi) { pa.u[0] = W[2 * jr * 2]; pa.u[1] = W[2 * jr * 2 + 1];
                   pa.u[2] = rA;            pa.u[3] = rB; }
        else     { pa.u[0] = rA;            pa.u[1] = rB;
                   pa.u[2] = W[(2 * jr + 1) * 2]; pa.u[3] = W[(2 * jr + 1) * 2 + 1]; }
        int j = s * 2 + jr;
        __builtin_amdgcn_s_setprio(1);
        bf16x8 vf0 = *(const bf16x8*)(Vp + (l31)*128 + (((2 * j + hi) ^ x7) << 4));
        ctx0 = __builtin_amdgcn_mfma_f32_32x32x16_bf16(pa.v, vf0, ctx0, 0, 0, 0);
        bf16x8 vf1 = *(const bf16x8*)(Vp + (32 + l31) * 128 + (((2 * j + hi) ^ x7) << 4));
        ctx1 = __builtin_amdgcn_mfma_f32_32x32x16_bf16(pa.v, vf1, ctx1, 0, 0, 0);
        __builtin_amdgcn_s_setprio(0);
      }
    }
  }

  if (!hi) red[wave][l31] = lr;
  asm volatile("s_waitcnt lgkmcnt(0)" ::: "memory");
  float* op = out + ((size_t)b * SEQ) * HDIM + h * 64 + l31;
#pragma unroll
  for (int r2 = 0; r2 < 4; ++r2) {
    f4v lv = *(const f4v*)(&red[wave][r2 * 8 + 4 * hi]);
#pragma unroll
    for (int j2 = 0; j2 < 4; ++j2) {
      float li = __builtin_amdgcn_rcpf(lv[j2]);
      int s = qrow0 + r2 * 8 + 4 * hi + j2;
      int r = r2 * 4 + j2;
      op[(size_t)s * HDIM]      = 0.5f * (c10[r] + ctx0[r] * li);
      op[(size_t)s * HDIM + 32] = 0.5f * (c11[r] + ctx1[r] * li);
    }
  }
}

// ---- host launcher ---------------------------------------------------------
extern "C" void kernel_launch(void* const* d_in, const int* in_sizes, int n_in,
                              void* d_out, int out_size, void* d_ws, size_t ws_size,
                              hipStream_t stream) {
  const float* hid = (const float*)d_in[0];
  const float* enc = (const float*)d_in[1];
  const float* amask = (const float*)d_in[2];
  const float* emask = (const float*)d_in[3];

  char* ws = (char*)d_ws;
  short* hbf = (short*)(ws);                        // 8 MB  [B*S,H] bf16
  short* ebf = (short*)(ws + (8u << 20));           // 4 MB  [B*K,H]
  short* wt = (short*)(ws + (12u << 20));           // 12 MB 6x [n][k]
  short* qo = (short*)(ws + (24u << 20));           // 8 MB  [B,NH,S,HD]
  short* ko = (short*)(ws + (32u << 20));           // 8 MB
  short* vT = (short*)(ws + (40u << 20));           // 8 MB  [B,NH,HD,S]
  short* kqo = (short*)(ws + (48u << 20));          // 8 MB
  short* kko = (short*)(ws + (56u << 20));          // 4 MB  [B,NH,K,HD]
  short* kvT = (short*)(ws + (60u << 20));          // 4 MB  [B,NH,HD,K]

  cast_bf16<<<4096, 256, 0, stream>>>(hid, hbf, (BATCH * SEQ * HDIM) / 4);
  cast_bf16<<<2048, 256, 0, stream>>>(enc, ebf, (BATCH * KENC * HDIM) / 4);

  WtArgs wa;
  for (int j = 0; j < 6; ++j) wa.W[j] = (const float*)d_in[4 + 2 * j];
  wt_cast<<<dim3(32, 32, 6), 256, 0, stream>>>(wa, wt);

  ProjArgs pa;
  const short* Xs[6] = {hbf, hbf, hbf, hbf, ebf, ebf};
  short* outs[6] = {qo, ko, vT, kqo, kko, kvT};
  const int Ms[6] = {4096, 4096, 4096, 4096, 2048, 2048};
  const int tsh[6] = {10, 10, 10, 10, 9, 9};
  const int md[6] = {0, 0, 1, 0, 0, 1};
  const float qscale = 0.125f * LOG2E;
  const float scl[6] = {qscale, 1.f, 1.f, qscale, 1.f, 1.f};
  for (int j = 0; j < 6; ++j) {
    pa.X[j] = Xs[j];
    pa.Wt[j] = wt + (size_t)j * (HDIM * HDIM);
    pa.bias[j] = (const float*)d_in[5 + 2 * j];
    pa.out[j] = outs[j];
    pa.M[j] = Ms[j];
    pa.tshift[j] = tsh[j];
    pa.mode[j] = md[j];
    pa.scale[j] = scl[j];
  }
  proj_gemm<<<dim3(8, 32, 6), 256, 0, stream>>>(pa);

  attn32<<<512, 256, 0, stream>>>(qo, ko, vT, kqo, kko, kvT, amask, emask,
                                  (float*)d_out);
}